// Round 1
// baseline (905.426 us; speedup 1.0000x reference)
//
#include <hip/hip_runtime.h>

namespace {
constexpr int NCB = 8;
constexpr int K   = 1024;
constexpr int CD  = 64;
constexpr int T   = 2048;
constexpr int B   = 8;
constexpr int D   = NCB * CD;            // 512
constexpr int TM  = 32;                  // tokens per block
constexpr int KT  = 128;                 // codebook rows per LDS tile
constexpr int LDK = CD + 4;              // padded LDS row stride (68 floats)
constexpr int NTH = 256;

constexpr long ZQ_OFF  = 0;
constexpr long IDX_OFF = (long)B * T * D;               // 8,388,608
constexpr long LG_OFF  = IDX_OFF + (long)B * NCB * T;   // 8,519,680
}

__global__ __launch_bounds__(NTH, 2)
void rvq_kernel(const float* __restrict__ Z, const float* __restrict__ CB,
                float* __restrict__ out)
{
    __shared__ float sCb[KT * LDK];    // 34,816 B
    __shared__ float sRes[TM * LDK];   //  8,704 B
    __shared__ float sCn2[KT];
    __shared__ float sRn2[TM];
    __shared__ int   sBest[TM];

    const int tid = threadIdx.x;
    const int kth = tid & 31;          // codeword lane
    const int grp = tid >> 5;          // token group: tokens [grp*4, grp*4+4)
    const int gt0 = blockIdx.x * TM;   // first global token (b*T + t)
    const int b   = gt0 / T;
    const int t0  = gt0 % T;

    float* __restrict__ zq  = out + ZQ_OFF;
    float* __restrict__ ido = out + IDX_OFF;
    float* __restrict__ lgo = out + LG_OFF;

    #pragma unroll 1
    for (int s = 0; s < NCB; ++s) {
        __syncthreads();   // prev-stage compute done; sBest visible

        // ---- residual update (and z_q write for stage s-1) ----
        #pragma unroll
        for (int r = 0; r < (TM * CD) / (4 * NTH); ++r) {   // 2 rounds
            const int f4  = tid + r * NTH;                  // float4 idx in [0,512)
            const int tok = f4 >> 4;
            const int dv  = f4 & 15;
            const float4 zv = *(const float4*)(Z + (long)(gt0 + tok) * D + s * CD + dv * 4);
            float4* rp = (float4*)(&sRes[tok * LDK + dv * 4]);
            if (s == 0) {
                *rp = zv;
            } else {
                const int best = sBest[tok];
                const float4 qv = *(const float4*)(CB + (long)((s - 1) * K + best) * CD + dv * 4);
                float4 rv = *rp;
                // match reference order: res_new = z_chunk + (res - q)
                rv.x = zv.x + (rv.x - qv.x);
                rv.y = zv.y + (rv.y - qv.y);
                rv.z = zv.z + (rv.z - qv.z);
                rv.w = zv.w + (rv.w - qv.w);
                *rp = rv;
                *(float4*)(zq + (long)(gt0 + tok) * D + (s - 1) * CD + dv * 4) = qv;
            }
        }
        __syncthreads();

        // ---- residual norms ----
        if (tid < TM) {
            const float4* rr = (const float4*)(&sRes[tid * LDK]);
            float a = 0.f;
            #pragma unroll
            for (int c = 0; c < CD / 4; ++c) {
                const float4 v = rr[c];
                a += v.x * v.x + v.y * v.y + v.z * v.z + v.w * v.w;
            }
            sRn2[tid] = a;
        }

        float bestv[4];
        int   besti[4];
        #pragma unroll
        for (int m = 0; m < 4; ++m) { bestv[m] = -3.4e38f; besti[m] = 0; }

        #pragma unroll 1
        for (int tile = 0; tile < K / KT; ++tile) {
            __syncthreads();   // prev tile compute done (and sRn2 ready for tile 0)

            // ---- stage KT x CD codebook tile into LDS ----
            const float4* src = (const float4*)(CB + (long)(s * K + tile * KT) * CD);
            #pragma unroll
            for (int r = 0; r < (KT * CD) / (4 * NTH); ++r) {   // 8 rounds
                const int f4 = tid + r * NTH;
                const int k  = f4 >> 4;
                const int dv = f4 & 15;
                *(float4*)(&sCb[k * LDK + dv * 4]) = src[f4];
            }
            __syncthreads();

            // ---- codeword norms for this tile ----
            if (tid < KT) {
                const float4* cr = (const float4*)(&sCb[tid * LDK]);
                float a = 0.f;
                #pragma unroll
                for (int c = 0; c < CD / 4; ++c) {
                    const float4 v = cr[c];
                    a += v.x * v.x + v.y * v.y + v.z * v.z + v.w * v.w;
                }
                sCn2[tid] = a;
            }
            __syncthreads();

            // ---- 4 tokens x 4 codewords register tile ----
            float acc[4][4];
            #pragma unroll
            for (int m = 0; m < 4; ++m)
                #pragma unroll
                for (int j = 0; j < 4; ++j) acc[m][j] = 0.f;

            const float4* crow[4];
            #pragma unroll
            for (int j = 0; j < 4; ++j)
                crow[j] = (const float4*)(&sCb[(j * 32 + kth) * LDK]);
            const float4* rrow[4];
            #pragma unroll
            for (int m = 0; m < 4; ++m)
                rrow[m] = (const float4*)(&sRes[(grp * 4 + m) * LDK]);

            #pragma unroll
            for (int dc = 0; dc < CD / 4; ++dc) {
                float4 rv[4];
                #pragma unroll
                for (int m = 0; m < 4; ++m) rv[m] = rrow[m][dc];
                #pragma unroll
                for (int j = 0; j < 4; ++j) {
                    const float4 cv = crow[j][dc];
                    #pragma unroll
                    for (int m = 0; m < 4; ++m) {
                        acc[m][j] += rv[m].x * cv.x + rv[m].y * cv.y
                                   + rv[m].z * cv.z + rv[m].w * cv.w;
                    }
                }
            }

            // ---- epilogue: logits + running argmax(-dist) ----
            const int kbase = tile * KT;
            float* lp0 = lgo + ((long)((b * NCB + s) * T + t0 + grp * 4) * K) + kbase + kth;
            #pragma unroll
            for (int m = 0; m < 4; ++m) {
                const float rn2 = sRn2[grp * 4 + m];
                float* lp = lp0 + (long)m * K;
                #pragma unroll
                for (int j = 0; j < 4; ++j) {
                    const float cn2 = sCn2[j * 32 + kth];
                    // logit = -(rn2 + cn2 - 2*dot)  (exact negation)
                    const float lg = 2.0f * acc[m][j] - (rn2 + cn2);
                    lp[j * 32] = lg;
                    const int kidx = kbase + j * 32 + kth;
                    if (lg > bestv[m]) { bestv[m] = lg; besti[m] = kidx; }
                }
            }
        }

        // ---- argmin reduce across the 32 codeword lanes of each group ----
        #pragma unroll
        for (int m = 0; m < 4; ++m) {
            float v  = bestv[m];
            int   ii = besti[m];
            #pragma unroll
            for (int off = 16; off > 0; off >>= 1) {
                const float ov = __shfl_xor(v, off);
                const int   oi = __shfl_xor(ii, off);
                if (ov > v || (ov == v && oi < ii)) { v = ov; ii = oi; }
            }
            if (kth == 0) {
                sBest[grp * 4 + m] = ii;
                ido[(long)(b * NCB + s) * T + t0 + grp * 4 + m] = (float)ii;
            }
        }
    }

    // ---- final z_q chunk (stage 7 quantization) ----
    __syncthreads();
    #pragma unroll
    for (int r = 0; r < (TM * CD) / (4 * NTH); ++r) {
        const int f4  = tid + r * NTH;
        const int tok = f4 >> 4;
        const int dv  = f4 & 15;
        const int best = sBest[tok];
        const float4 qv = *(const float4*)(CB + (long)(7 * K + best) * CD + dv * 4);
        *(float4*)(zq + (long)(gt0 + tok) * D + 7 * CD + dv * 4) = qv;
    }
}

extern "C" void kernel_launch(void* const* d_in, const int* in_sizes, int n_in,
                              void* d_out, int out_size, void* d_ws, size_t ws_size,
                              hipStream_t stream)
{
    const float* Z   = (const float*)d_in[0];
    const float* CBp = (const float*)d_in[1];
    float* out = (float*)d_out;

    dim3 grid((B * T) / TM);   // 512 blocks
    dim3 block(NTH);
    hipLaunchKernelGGL(rvq_kernel, grid, block, 0, stream, Z, CBp, out);
}